// Round 3
// baseline (579.948 us; speedup 1.0000x reference)
//
#include <hip/hip_runtime.h>
#include <math.h>

#define NN 512
#define BB 128
#define CIN 66
#define QQ (BB*CIN)            // 8448
#define AN ((size_t)NN*NN)
#define HROWS 264              // compact H rows per b: 66 XT + 3*66 hop1
#define KTOT 480               // padded concat-K (462 real)
#define HTROW 480

typedef unsigned short ushort_t;
typedef __attribute__((ext_vector_type(8))) short short8;
typedef __attribute__((ext_vector_type(4))) float f32x4;
typedef __attribute__((ext_vector_type(4))) unsigned short us4;

__device__ __forceinline__ ushort_t f2bf(float f) {
    unsigned u = __float_as_uint(f);
    u += 0x7FFF + ((u >> 16) & 1);
    return (ushort_t)(u >> 16);
}
__device__ __forceinline__ float bf2f(ushort_t h) {
    return __uint_as_float(((unsigned)h) << 16);
}
__device__ __forceinline__ void split_bf(float f, ushort_t& hi, ushort_t& lo) {
    hi = f2bf(f);
    lo = f2bf(f - bf2f(hi));
}
__device__ __forceinline__ void gload_lds16(const void* g, void* l) {
    __builtin_amdgcn_global_load_lds(
        (const __attribute__((address_space(1))) unsigned*)g,
        (__attribute__((address_space(3))) unsigned*)l, 16, 0, 0);
}

// ---------- adp = row-softmax(relu(nv1 @ nv2)) ----------
__global__ __launch_bounds__(512) void adp_kernel(const float* __restrict__ nv1,
                                                  const float* __restrict__ nv2,
                                                  float* __restrict__ adp) {
    int n = blockIdx.x;
    int m = threadIdx.x;
    float z = 0.f;
#pragma unroll
    for (int k = 0; k < 10; k++) z = fmaf(nv1[n * 10 + k], nv2[k * NN + m], z);
    z = fmaxf(z, 0.f);

    __shared__ float sred[8];
    int wid  = threadIdx.x >> 6;
    int lane = threadIdx.x & 63;

    float v = z;
#pragma unroll
    for (int off = 32; off; off >>= 1) v = fmaxf(v, __shfl_down(v, off, 64));
    if (lane == 0) sred[wid] = v;
    __syncthreads();
    float zmax = sred[0];
#pragma unroll
    for (int i = 1; i < 8; i++) zmax = fmaxf(zmax, sred[i]);

    float e = __expf(z - zmax);
    __syncthreads();
    v = e;
#pragma unroll
    for (int off = 32; off; off >>= 1) v += __shfl_down(v, off, 64);
    if (lane == 0) sred[wid] = v;
    __syncthreads();
    float tot = 0.f;
#pragma unroll
    for (int i = 0; i < 8; i++) tot += sred[i];

    adp[n * NN + m] = e / tot;
}

// ---------- transpose + bf16-split the 4 supports: Ahi/Alo[s][m][k] ----------
__global__ __launch_bounds__(256) void asplit_kernel(const float* __restrict__ A0,
                                                     const float* __restrict__ A1,
                                                     const float* __restrict__ P1,
                                                     const float* __restrict__ P2,
                                                     ushort_t* __restrict__ Ahi,
                                                     ushort_t* __restrict__ Alo) {
    __shared__ float t[32][33];
    int s = blockIdx.z;
    const float* src = (s == 0) ? A0 : (s == 1) ? A1 : (s == 2) ? P1 : P2;
    int m0 = blockIdx.x * 32, k0 = blockIdx.y * 32;
    int tx = threadIdx.x & 31, ty = threadIdx.x >> 5;
#pragma unroll
    for (int r = 0; r < 32; r += 8)
        t[ty + r][tx] = src[(size_t)(k0 + ty + r) * NN + m0 + tx];
    __syncthreads();
#pragma unroll
    for (int r = 0; r < 32; r += 8) {
        int m = m0 + ty + r, k = k0 + tx;
        float v = t[tx][ty + r];
        ushort_t h, l; split_bf(v, h, l);
        size_t o = ((size_t)s * NN + m) * NN + k;
        Ahi[o] = h; Alo[o] = l;
    }
}

// ---------- Wt[j][KTOT] = split(W[k][j]), zero-padded ----------
template <int COUT>
__global__ __launch_bounds__(256) void wtprep_kernel(const float* __restrict__ W,
                                                     ushort_t* __restrict__ Wth,
                                                     ushort_t* __restrict__ Wtl) {
    int j = blockIdx.x;
    for (int k = threadIdx.x; k < KTOT; k += 256) {
        float v = (k < 462) ? W[(size_t)k * COUT + j] : 0.f;
        ushort_t h, l; split_bf(v, h, l);
        Wth[(size_t)j * KTOT + k] = h;
        Wtl[(size_t)j * KTOT + k] = l;
    }
}

// ---------- zero Ht pad rows k in [462,480) ----------
__global__ __launch_bounds__(256) void zeroht_kernel(ushort_t* __restrict__ Hth,
                                                     ushort_t* __restrict__ Htl) {
    size_t row = blockIdx.x * 256 + threadIdx.x;   // b*512+n, 65536 rows
    unsigned* ph = (unsigned*)(Hth + row * HTROW + 462);
    unsigned* pl = (unsigned*)(Htl + row * HTROW + 462);
#pragma unroll
    for (int i = 0; i < 9; i++) { ph[i] = 0; pl[i] = 0; }
}

// ---------- build XT: H rows 0..65 (n-contig) + Ht k 0..65 (k-contig) ----------
__global__ __launch_bounds__(256) void buildx_kernel(const float* __restrict__ inp,
                                                     const float* __restrict__ st,
                                                     ushort_t* Hh, ushort_t* Hl,
                                                     ushort_t* Hth, ushort_t* Htl) {
    int b = blockIdx.y, n = blockIdx.x * 64 + (threadIdx.x & 63);
    int cg = threadIdx.x >> 6;
    size_t bn = (size_t)b * NN + n;
    for (int c = cg; c < CIN; c += 4) {
        float v = (c < 2) ? inp[bn * 2 + c] : st[bn * 64 + (c - 2)];
        ushort_t h, l; split_bf(v, h, l);
        Hh[((size_t)b * HROWS + c) * NN + n] = h;
        Hl[((size_t)b * HROWS + c) * NN + n] = l;
        Hth[bn * HTROW + c] = h;
        Htl[bn * HTROW + c] = l;
    }
}

// ---------- diffusion GEMM (MFMA, split-bf16) ----------
// HOP1: reads H rows c (XT), writes H rows 66+66s+c  AND Ht k=66+132s+c
// HOP2: reads H rows 66+66s+c, writes Ht k=132+132s+c only
template <int HOP>
__global__ __launch_bounds__(256) void diff_mfma(const ushort_t* __restrict__ Ahi,
                                                 const ushort_t* __restrict__ Alo,
                                                 const ushort_t* Hh, const ushort_t* Hl,
                                                 ushort_t* Hth, ushort_t* Htl,
                                                 int s2) {
    __shared__ ushort_t sAh[128 * 32];
    __shared__ ushort_t sAl[128 * 32];
    __shared__ ushort_t sXh[128 * 32];
    __shared__ ushort_t sXl[128 * 32];
    const int tid  = threadIdx.x;
    const int lane = tid & 63, w = tid >> 6;
    const int quad = lane >> 4, l15 = lane & 15;
    const int q0 = blockIdx.x * 128, m0 = blockIdx.y * 128;
    const int sz = blockIdx.z;
    const int sup = (sz < 2) ? sz : s2;
    const ushort_t* Ah = Ahi + (size_t)sup * AN;
    const ushort_t* Al = Alo + (size_t)sup * AN;
    const int roff_in = (HOP == 1) ? 0 : 66 + 66 * sz;
    const int wm = w & 1, wq = w >> 1;

    size_t aoff[2], xoff[2];
    int ldo[2];
#pragma unroll
    for (int p = 0; p < 2; p++) {
        int cid = p * 256 + tid;
        int row = cid >> 2, kk = (cid & 3) * 8;
        ldo[p]  = cid * 8;
        aoff[p] = (size_t)(m0 + row) * NN + kk;
        int q = q0 + row, b = q / 66, c = q - 66 * b;
        xoff[p] = ((size_t)b * HROWS + roff_in + c) * NN + kk;
    }

    f32x4 acc[4][4] = {};

    for (int k0 = 0; k0 < NN; k0 += 32) {
        __syncthreads();
#pragma unroll
        for (int p = 0; p < 2; p++) {
            gload_lds16(Ah + aoff[p] + k0, sAh + ldo[p]);
            gload_lds16(Al + aoff[p] + k0, sAl + ldo[p]);
            gload_lds16(Hh + xoff[p] + k0, sXh + ldo[p]);
            gload_lds16(Hl + xoff[p] + k0, sXl + ldo[p]);
        }
        __syncthreads();
        short8 ah[4], al[4], xh[4], xl[4];
#pragma unroll
        for (int t = 0; t < 4; t++) {
            int arow = wm * 64 + t * 16 + l15;
            int xrow = wq * 64 + t * 16 + l15;
            ah[t] = *(const short8*)&sAh[arow * 32 + quad * 8];
            al[t] = *(const short8*)&sAl[arow * 32 + quad * 8];
            xh[t] = *(const short8*)&sXh[xrow * 32 + quad * 8];
            xl[t] = *(const short8*)&sXl[xrow * 32 + quad * 8];
        }
#pragma unroll
        for (int mt = 0; mt < 4; mt++)
#pragma unroll
            for (int qt = 0; qt < 4; qt++) {
                acc[mt][qt] = __builtin_amdgcn_mfma_f32_16x16x32_bf16(ah[mt], xh[qt], acc[mt][qt], 0, 0, 0);
                acc[mt][qt] = __builtin_amdgcn_mfma_f32_16x16x32_bf16(ah[mt], xl[qt], acc[mt][qt], 0, 0, 0);
                acc[mt][qt] = __builtin_amdgcn_mfma_f32_16x16x32_bf16(al[mt], xh[qt], acc[mt][qt], 0, 0, 0);
            }
    }

    const int koff = (HOP == 1) ? 66 + 132 * sz : 132 + 132 * sz;
    const int hoff = 66 + 66 * sz;
#pragma unroll
    for (int qt = 0; qt < 4; qt++) {
        int q = q0 + wq * 64 + qt * 16 + l15;
        int b = q / 66, c = q - 66 * b;
#pragma unroll
        for (int mt = 0; mt < 4; mt++) {
            int mb = wm * 64 + mt * 16 + quad * 4;
            int n  = m0 + mb;
            us4 h4, l4;
#pragma unroll
            for (int r = 0; r < 4; r++) {
                ushort_t h, l; split_bf(acc[mt][qt][r], h, l);
                h4[r] = h; l4[r] = l;
            }
            if (HOP == 1) {
                size_t ho = ((size_t)b * HROWS + hoff + c) * NN + n;
                *(us4*)&Hh[ho] = h4;   // safe: rows disjoint from read range
                *(us4*)&Hl[ho] = l4;
            }
            size_t tb = ((size_t)b * NN + n) * HTROW + koff + c;
#pragma unroll
            for (int r = 0; r < 4; r++) {
                Hth[tb + (size_t)r * HTROW] = h4[r];
                Htl[tb + (size_t)r * HTROW] = l4[r];
            }
        }
    }
}

// ---------- projection GEMM (MFMA, split-bf16) over Ht ----------
// out[n][j] = sum_k Ht[b][n][k] * Wt[j][k]   (K = 480, 15 steps)
// LAYER1 (COUT=128, BM=128): sigmoid; j<64 -> r*state into H rows 2+j and Ht k=2+j; j>=64 -> U
// LAYER2 (COUT=64, BM=256): tanh + gate -> out
template <int COUT, int LAYER, int BM>
__global__ __launch_bounds__(256) void proj_mfma(ushort_t* Hth, ushort_t* Htl,
                                                 const ushort_t* __restrict__ Wth,
                                                 const ushort_t* __restrict__ Wtl,
                                                 const float* __restrict__ bias,
                                                 const float* __restrict__ state,
                                                 float* U,
                                                 ushort_t* Hh, ushort_t* Hl,
                                                 float* __restrict__ out) {
    __shared__ ushort_t sAh[BM * 32];
    __shared__ ushort_t sAl[BM * 32];
    __shared__ ushort_t sBh[COUT * 32];
    __shared__ ushort_t sBl[COUT * 32];
    constexpr int PA = BM / 64;
    constexpr int PB = COUT / 64;
    const int tid  = threadIdx.x;
    const int lane = tid & 63, w = tid >> 6;
    const int quad = lane >> 4, l15 = lane & 15;
    const int b = blockIdx.y, n0 = blockIdx.x * BM;
    const int wn = (COUT == 128) ? (w & 1) : w;
    const int wj = (COUT == 128) ? (w >> 1) : 0;

    size_t aoff[PA]; int lA[PA];
#pragma unroll
    for (int p = 0; p < PA; p++) {
        int cid = p * 256 + tid;
        int row = cid >> 2, kk = (cid & 3) * 8;
        lA[p]   = cid * 8;
        aoff[p] = ((size_t)b * NN + n0 + row) * HTROW + kk;
    }
    size_t boff[PB]; int lB[PB];
#pragma unroll
    for (int p = 0; p < PB; p++) {
        int cid = p * 256 + tid;
        int row = cid >> 2, kk = (cid & 3) * 8;
        lB[p]   = cid * 8;
        boff[p] = (size_t)row * KTOT + kk;
    }

    f32x4 acc[4][4] = {};

    for (int k0 = 0; k0 < KTOT; k0 += 32) {
        __syncthreads();
#pragma unroll
        for (int p = 0; p < PA; p++) {
            gload_lds16(Hth + aoff[p] + k0, sAh + lA[p]);
            gload_lds16(Htl + aoff[p] + k0, sAl + lA[p]);
        }
#pragma unroll
        for (int p = 0; p < PB; p++) {
            gload_lds16(Wth + boff[p] + k0, sBh + lB[p]);
            gload_lds16(Wtl + boff[p] + k0, sBl + lB[p]);
        }
        __syncthreads();
        short8 ah[4], al[4], bh[4], bl[4];
#pragma unroll
        for (int t = 0; t < 4; t++) {
            int arow = wn * 64 + t * 16 + l15;
            int brow = wj * 64 + t * 16 + l15;
            ah[t] = *(const short8*)&sAh[arow * 32 + quad * 8];
            al[t] = *(const short8*)&sAl[arow * 32 + quad * 8];
            bh[t] = *(const short8*)&sBh[brow * 32 + quad * 8];
            bl[t] = *(const short8*)&sBl[brow * 32 + quad * 8];
        }
#pragma unroll
        for (int nt = 0; nt < 4; nt++)
#pragma unroll
            for (int jt = 0; jt < 4; jt++) {
                acc[nt][jt] = __builtin_amdgcn_mfma_f32_16x16x32_bf16(ah[nt], bh[jt], acc[nt][jt], 0, 0, 0);
                acc[nt][jt] = __builtin_amdgcn_mfma_f32_16x16x32_bf16(ah[nt], bl[jt], acc[nt][jt], 0, 0, 0);
                acc[nt][jt] = __builtin_amdgcn_mfma_f32_16x16x32_bf16(al[nt], bh[jt], acc[nt][jt], 0, 0, 0);
            }
    }

#pragma unroll
    for (int jt = 0; jt < 4; jt++) {
        int j = wj * 64 + jt * 16 + l15;
        float bj = bias[j];
#pragma unroll
        for (int nt = 0; nt < 4; nt++) {
            int nb = n0 + wn * 64 + nt * 16 + quad * 4;
            f32x4 z = acc[nt][jt];
#pragma unroll
            for (int r = 0; r < 4; r++) z[r] += bj;
            if (LAYER == 1) {
#pragma unroll
                for (int r = 0; r < 4; r++) z[r] = 1.f / (1.f + __expf(-z[r]));
                if (j < 64) {
                    us4 h4, l4;
#pragma unroll
                    for (int r = 0; r < 4; r++) {
                        float x2 = z[r] * state[((size_t)b * NN + nb + r) * 64 + j];
                        ushort_t h, l; split_bf(x2, h, l);
                        h4[r] = h; l4[r] = l;
                    }
                    size_t ho = ((size_t)b * HROWS + 2 + j) * NN + nb;
                    *(us4*)&Hh[ho] = h4;
                    *(us4*)&Hl[ho] = l4;
                    size_t tb = ((size_t)b * NN + nb) * HTROW + 2 + j;
#pragma unroll
                    for (int r = 0; r < 4; r++) {
                        Hth[tb + (size_t)r * HTROW] = h4[r];
                        Htl[tb + (size_t)r * HTROW] = l4[r];
                    }
                } else {
                    *(f32x4*)&U[((size_t)b * 64 + j - 64) * NN + nb] = z;
                }
            } else {
                f32x4 u4 = *(const f32x4*)&U[((size_t)b * 64 + j) * NN + nb];
#pragma unroll
                for (int r = 0; r < 4; r++) {
                    float c = tanhf(z[r]);
                    float s = state[((size_t)b * NN + nb + r) * 64 + j];
                    out[((size_t)b * NN + nb + r) * 64 + j] = u4[r] * s + (1.f - u4[r]) * c;
                }
            }
        }
    }
}

extern "C" void kernel_launch(void* const* d_in, const int* in_sizes, int n_in,
                              void* d_out, int out_size, void* d_ws, size_t ws_size,
                              hipStream_t stream) {
    const float* input = (const float*)d_in[0];
    const float* state = (const float*)d_in[1];
    const float* A0    = (const float*)d_in[2];
    const float* A1    = (const float*)d_in[3];
    const float* nv1_1 = (const float*)d_in[4];
    const float* nv2_1 = (const float*)d_in[5];
    const float* W1    = (const float*)d_in[6];
    const float* b1    = (const float*)d_in[7];
    const float* nv1_2 = (const float*)d_in[8];
    const float* nv2_2 = (const float*)d_in[9];
    const float* W2    = (const float*)d_in[10];
    const float* b2    = (const float*)d_in[11];
    float* out = (float*)d_out;

    char* p = (char*)d_ws;
    auto alloc = [&](size_t bytes) { void* r = (void*)p; p += (bytes + 255) & ~(size_t)255; return r; };
    float*    ADP1 = (float*)alloc(AN * 4);
    float*    ADP2 = (float*)alloc(AN * 4);
    ushort_t* Ahi  = (ushort_t*)alloc(4 * AN * 2);
    ushort_t* Alo  = (ushort_t*)alloc(4 * AN * 2);
    ushort_t* Hh   = (ushort_t*)alloc((size_t)BB * HROWS * NN * 2);
    ushort_t* Hl   = (ushort_t*)alloc((size_t)BB * HROWS * NN * 2);
    ushort_t* Hth  = (ushort_t*)alloc((size_t)BB * NN * HTROW * 2);
    ushort_t* Htl  = (ushort_t*)alloc((size_t)BB * NN * HTROW * 2);
    ushort_t* Wt1h = (ushort_t*)alloc((size_t)128 * KTOT * 2);
    ushort_t* Wt1l = (ushort_t*)alloc((size_t)128 * KTOT * 2);
    ushort_t* Wt2h = (ushort_t*)alloc((size_t)64 * KTOT * 2);
    ushort_t* Wt2l = (ushort_t*)alloc((size_t)64 * KTOT * 2);
    float*    U    = (float*)alloc((size_t)BB * 64 * NN * 4);

    adp_kernel<<<NN, NN, 0, stream>>>(nv1_1, nv2_1, ADP1);
    adp_kernel<<<NN, NN, 0, stream>>>(nv1_2, nv2_2, ADP2);
    asplit_kernel<<<dim3(16, 16, 4), 256, 0, stream>>>(A0, A1, ADP1, ADP2, Ahi, Alo);
    wtprep_kernel<128><<<128, 256, 0, stream>>>(W1, Wt1h, Wt1l);
    wtprep_kernel<64><<<64, 256, 0, stream>>>(W2, Wt2h, Wt2l);
    zeroht_kernel<<<BB * NN / 256, 256, 0, stream>>>(Hth, Htl);
    buildx_kernel<<<dim3(8, BB), 256, 0, stream>>>(input, state, Hh, Hl, Hth, Htl);

    dim3 gd(QQ / 128, 4, 3);
    // layer 1
    diff_mfma<1><<<gd, 256, 0, stream>>>(Ahi, Alo, Hh, Hl, Hth, Htl, 2);
    diff_mfma<2><<<gd, 256, 0, stream>>>(Ahi, Alo, Hh, Hl, Hth, Htl, 2);
    proj_mfma<128, 1, 128><<<dim3(4, BB), 256, 0, stream>>>(Hth, Htl, Wt1h, Wt1l, b1, state,
                                                            U, Hh, Hl, nullptr);
    // layer 2 (H rows 2..65 and Ht k 2..65 now hold r*state)
    diff_mfma<1><<<gd, 256, 0, stream>>>(Ahi, Alo, Hh, Hl, Hth, Htl, 3);
    diff_mfma<2><<<gd, 256, 0, stream>>>(Ahi, Alo, Hh, Hl, Hth, Htl, 3);
    proj_mfma<64, 2, 256><<<dim3(2, BB), 256, 0, stream>>>(Hth, Htl, Wt2h, Wt2l, b2, state,
                                                           U, nullptr, nullptr, out);
}

// Round 4
// 486.071 us; speedup vs baseline: 1.1931x; 1.1931x over previous
//
#include <hip/hip_runtime.h>
#include <math.h>

#define NN 512
#define BB 128
#define CIN 66
#define QQ (BB*CIN)            // 8448
#define AN ((size_t)NN*NN)
#define HB 480                 // H rows per batch: 462 used (7 segs x 66), pad garbage-safe
#define KTOT 480               // padded K for proj (Wt rows 462..479 are zero)

typedef unsigned short ushort_t;
typedef __attribute__((ext_vector_type(8))) short short8;
typedef __attribute__((ext_vector_type(8))) unsigned short us8;
typedef __attribute__((ext_vector_type(4))) float f32x4;
typedef __attribute__((ext_vector_type(4))) unsigned short us4;

__device__ __forceinline__ ushort_t f2bf(float f) {
    unsigned u = __float_as_uint(f);
    u += 0x7FFF + ((u >> 16) & 1);
    return (ushort_t)(u >> 16);
}
__device__ __forceinline__ float bf2f(ushort_t h) {
    return __uint_as_float(((unsigned)h) << 16);
}
__device__ __forceinline__ void split_bf(float f, ushort_t& hi, ushort_t& lo) {
    hi = f2bf(f);
    lo = f2bf(f - bf2f(hi));
}
__device__ __forceinline__ void gload_lds16(const void* g, void* l) {
    __builtin_amdgcn_global_load_lds(
        (const __attribute__((address_space(1))) unsigned*)g,
        (__attribute__((address_space(3))) unsigned*)l, 16, 0, 0);
}

// ---------- adp = row-softmax(relu(nv1 @ nv2)) ----------
__global__ __launch_bounds__(512) void adp_kernel(const float* __restrict__ nv1,
                                                  const float* __restrict__ nv2,
                                                  float* __restrict__ adp) {
    int n = blockIdx.x;
    int m = threadIdx.x;
    float z = 0.f;
#pragma unroll
    for (int k = 0; k < 10; k++) z = fmaf(nv1[n * 10 + k], nv2[k * NN + m], z);
    z = fmaxf(z, 0.f);

    __shared__ float sred[8];
    int wid  = threadIdx.x >> 6;
    int lane = threadIdx.x & 63;

    float v = z;
#pragma unroll
    for (int off = 32; off; off >>= 1) v = fmaxf(v, __shfl_down(v, off, 64));
    if (lane == 0) sred[wid] = v;
    __syncthreads();
    float zmax = sred[0];
#pragma unroll
    for (int i = 1; i < 8; i++) zmax = fmaxf(zmax, sred[i]);

    float e = __expf(z - zmax);
    __syncthreads();
    v = e;
#pragma unroll
    for (int off = 32; off; off >>= 1) v += __shfl_down(v, off, 64);
    if (lane == 0) sred[wid] = v;
    __syncthreads();
    float tot = 0.f;
#pragma unroll
    for (int i = 0; i < 8; i++) tot += sred[i];

    adp[n * NN + m] = e / tot;
}

// ---------- transpose + bf16-split the 4 supports: Ahi/Alo[s][m][k] ----------
__global__ __launch_bounds__(256) void asplit_kernel(const float* __restrict__ A0,
                                                     const float* __restrict__ A1,
                                                     const float* __restrict__ P1,
                                                     const float* __restrict__ P2,
                                                     ushort_t* __restrict__ Ahi,
                                                     ushort_t* __restrict__ Alo) {
    __shared__ float t[32][33];
    int s = blockIdx.z;
    const float* src = (s == 0) ? A0 : (s == 1) ? A1 : (s == 2) ? P1 : P2;
    int m0 = blockIdx.x * 32, k0 = blockIdx.y * 32;
    int tx = threadIdx.x & 31, ty = threadIdx.x >> 5;
#pragma unroll
    for (int r = 0; r < 32; r += 8)
        t[ty + r][tx] = src[(size_t)(k0 + ty + r) * NN + m0 + tx];
    __syncthreads();
#pragma unroll
    for (int r = 0; r < 32; r += 8) {
        int m = m0 + ty + r, k = k0 + tx;
        float v = t[tx][ty + r];
        ushort_t h, l; split_bf(v, h, l);
        size_t o = ((size_t)s * NN + m) * NN + k;
        Ahi[o] = h; Alo[o] = l;
    }
}

// ---------- Wt[j][KTOT] = split(W[k][j]), zero-padded ----------
template <int COUT>
__global__ __launch_bounds__(256) void wtprep_kernel(const float* __restrict__ W,
                                                     ushort_t* __restrict__ Wth,
                                                     ushort_t* __restrict__ Wtl) {
    int j = blockIdx.x;
    for (int k = threadIdx.x; k < KTOT; k += 256) {
        float v = (k < 462) ? W[(size_t)k * COUT + j] : 0.f;
        ushort_t h, l; split_bf(v, h, l);
        Wth[(size_t)j * KTOT + k] = h;
        Wtl[(size_t)j * KTOT + k] = l;
    }
}

// ---------- build XT: H rows 0..65 (n-contig) ----------
__global__ __launch_bounds__(256) void buildx_kernel(const float* __restrict__ inp,
                                                     const float* __restrict__ st,
                                                     ushort_t* __restrict__ Hh,
                                                     ushort_t* __restrict__ Hl) {
    int b = blockIdx.y, n = blockIdx.x * 64 + (threadIdx.x & 63);
    int cg = threadIdx.x >> 6;
    size_t bn = (size_t)b * NN + n;
    for (int c = cg; c < CIN; c += 4) {
        float v = (c < 2) ? inp[bn * 2 + c] : st[bn * 64 + (c - 2)];
        ushort_t h, l; split_bf(v, h, l);
        Hh[((size_t)b * HB + c) * NN + n] = h;
        Hl[((size_t)b * HB + c) * NN + n] = l;
    }
}

// ---------- diffusion GEMM (MFMA, split-bf16): writes n-contig H rows only ----------
// seg layout per b (rows of H): 0..65 = x; 66+132s = x1(sup s); 132+132s = x2(sup s)
// HOP1: reads rows 0..65, writes rows 66+132s.  HOP2: reads 66+132s, writes 132+132s.
template <int HOP>
__global__ __launch_bounds__(256) void diff_mfma(const ushort_t* __restrict__ Ahi,
                                                 const ushort_t* __restrict__ Alo,
                                                 ushort_t* Hh, ushort_t* Hl, int s2) {
    __shared__ ushort_t sAh[128 * 32];
    __shared__ ushort_t sAl[128 * 32];
    __shared__ ushort_t sXh[128 * 32];
    __shared__ ushort_t sXl[128 * 32];
    const int tid  = threadIdx.x;
    const int lane = tid & 63, w = tid >> 6;
    const int quad = lane >> 4, l15 = lane & 15;
    const int q0 = blockIdx.x * 128, m0 = blockIdx.y * 128;
    const int sz = blockIdx.z;
    const int sup = (sz < 2) ? sz : s2;
    const ushort_t* Ah = Ahi + (size_t)sup * AN;
    const ushort_t* Al = Alo + (size_t)sup * AN;
    const int roff_in = (HOP == 1) ? 0 : 66 + 132 * sz;
    const int wm = w & 1, wq = w >> 1;

    size_t aoff[2], xoff[2];
    int ldo[2];
#pragma unroll
    for (int p = 0; p < 2; p++) {
        int cid = p * 256 + tid;
        int row = cid >> 2, kk = (cid & 3) * 8;
        ldo[p]  = cid * 8;
        aoff[p] = (size_t)(m0 + row) * NN + kk;
        int q = q0 + row, b = q / 66, c = q - 66 * b;
        xoff[p] = ((size_t)b * HB + roff_in + c) * NN + kk;
    }

    f32x4 acc[4][4] = {};

    for (int k0 = 0; k0 < NN; k0 += 32) {
        __syncthreads();
#pragma unroll
        for (int p = 0; p < 2; p++) {
            gload_lds16(Ah + aoff[p] + k0, sAh + ldo[p]);
            gload_lds16(Al + aoff[p] + k0, sAl + ldo[p]);
            gload_lds16(Hh + xoff[p] + k0, sXh + ldo[p]);
            gload_lds16(Hl + xoff[p] + k0, sXl + ldo[p]);
        }
        __syncthreads();
        short8 ah[4], al[4], xh[4], xl[4];
#pragma unroll
        for (int t = 0; t < 4; t++) {
            int arow = wm * 64 + t * 16 + l15;
            int xrow = wq * 64 + t * 16 + l15;
            ah[t] = *(const short8*)&sAh[arow * 32 + quad * 8];
            al[t] = *(const short8*)&sAl[arow * 32 + quad * 8];
            xh[t] = *(const short8*)&sXh[xrow * 32 + quad * 8];
            xl[t] = *(const short8*)&sXl[xrow * 32 + quad * 8];
        }
#pragma unroll
        for (int mt = 0; mt < 4; mt++)
#pragma unroll
            for (int qt = 0; qt < 4; qt++) {
                acc[mt][qt] = __builtin_amdgcn_mfma_f32_16x16x32_bf16(ah[mt], xh[qt], acc[mt][qt], 0, 0, 0);
                acc[mt][qt] = __builtin_amdgcn_mfma_f32_16x16x32_bf16(ah[mt], xl[qt], acc[mt][qt], 0, 0, 0);
                acc[mt][qt] = __builtin_amdgcn_mfma_f32_16x16x32_bf16(al[mt], xh[qt], acc[mt][qt], 0, 0, 0);
                acc[mt][qt] = __builtin_amdgcn_mfma_f32_16x16x32_bf16(al[mt], xl[qt], acc[mt][qt], 0, 0, 0);
            }
    }

    const int rowo = (HOP == 1) ? 66 + 132 * sz : 132 + 132 * sz;
#pragma unroll
    for (int qt = 0; qt < 4; qt++) {
        int q = q0 + wq * 64 + qt * 16 + l15;
        int b = q / 66, c = q - 66 * b;
#pragma unroll
        for (int mt = 0; mt < 4; mt++) {
            int n = m0 + wm * 64 + mt * 16 + quad * 4;
            us4 h4, l4;
#pragma unroll
            for (int r = 0; r < 4; r++) {
                ushort_t h, l; split_bf(acc[mt][qt][r], h, l);
                h4[r] = h; l4[r] = l;
            }
            size_t ho = ((size_t)b * HB + rowo + c) * NN + n;
            *(us4*)&Hh[ho] = h4;
            *(us4*)&Hl[ho] = l4;
        }
    }
}

// ---------- projection GEMM (MFMA, split-bf16), A transposed in LDS staging ----------
// out[n][j] = sum_k H[b][k][n] * Wt[j][k]   (K = 480, 15 steps of 32)
// LAYER1 (COUT=128, BM=128): sigmoid; j<64 -> r*state into H rows 2+j; j>=64 -> U
// LAYER2 (COUT=64, BM=256): tanh + gate -> out
template <int COUT, int LAYER, int BM>
__global__ __launch_bounds__(256) void proj_mfma(const ushort_t* HhC, const ushort_t* HlC,
                                                 const ushort_t* __restrict__ Wth,
                                                 const ushort_t* __restrict__ Wtl,
                                                 const float* __restrict__ bias,
                                                 const float* __restrict__ state,
                                                 float* U,
                                                 ushort_t* Hhw, ushort_t* Hlw,
                                                 float* __restrict__ out) {
    __shared__ ushort_t sAh[BM * 32];
    __shared__ ushort_t sAl[BM * 32];
    __shared__ ushort_t sBh[COUT * 32];
    __shared__ ushort_t sBl[COUT * 32];
    constexpr int PB = COUT / 64;
    const int tid  = threadIdx.x;
    const int lane = tid & 63, w = tid >> 6;
    const int quad = lane >> 4, l15 = lane & 15;
    const int b = blockIdx.y, n0 = blockIdx.x * BM;
    const int wn = (COUT == 128) ? (w & 1) : w;
    const int wj = (COUT == 128) ? (w >> 1) : 0;
    const int kp = tid & 15, n8 = tid >> 4;

    size_t boff[PB]; int lB[PB];
#pragma unroll
    for (int p = 0; p < PB; p++) {
        int cid = p * 256 + tid;
        lB[p]   = cid * 8;
        boff[p] = (size_t)(cid >> 2) * KTOT + (cid & 3) * 8;
    }

    f32x4 acc[4][4] = {};

    for (int k0 = 0; k0 < KTOT; k0 += 32) {
        __syncthreads();
        // ---- A: load H[k][n] coalesced, write transposed (k-pairs) into sAt[n][k] ----
#pragma unroll
        for (int pass = 0; pass < BM / 128; pass++) {
            int np0 = (n8 + pass * 16) * 8;
            int kk  = k0 + 2 * kp;
            const ushort_t* sh = HhC + ((size_t)b * HB + kk) * NN + n0 + np0;
            const ushort_t* sl = HlC + ((size_t)b * HB + kk) * NN + n0 + np0;
            us8 h0 = *(const us8*)sh;
            us8 h1 = *(const us8*)(sh + NN);
            us8 l0 = *(const us8*)sl;
            us8 l1 = *(const us8*)(sl + NN);
            int g = kp >> 2, ko = (2 * kp) & 7;
#pragma unroll
            for (int j2 = 0; j2 < 8; j2++) {
                int n   = np0 + j2;
                int idx = n * 32 + ((g ^ ((n >> 1) & 3)) << 3) + ko;
                *(unsigned*)&sAh[idx] = (unsigned)h0[j2] | ((unsigned)h1[j2] << 16);
                *(unsigned*)&sAl[idx] = (unsigned)l0[j2] | ((unsigned)l1[j2] << 16);
            }
        }
        // ---- B: k-contiguous async staging ----
#pragma unroll
        for (int p = 0; p < PB; p++) {
            gload_lds16(Wth + boff[p] + k0, sBh + lB[p]);
            gload_lds16(Wtl + boff[p] + k0, sBl + lB[p]);
        }
        __syncthreads();
        short8 ah[4], al[4], bh[4], bl[4];
#pragma unroll
        for (int t = 0; t < 4; t++) {
            int an  = wn * 64 + t * 16 + l15;
            int ago = (quad ^ ((an >> 1) & 3)) << 3;
            ah[t] = *(const short8*)&sAh[an * 32 + ago];
            al[t] = *(const short8*)&sAl[an * 32 + ago];
            int brow = wj * 64 + t * 16 + l15;
            bh[t] = *(const short8*)&sBh[brow * 32 + quad * 8];
            bl[t] = *(const short8*)&sBl[brow * 32 + quad * 8];
        }
#pragma unroll
        for (int nt = 0; nt < 4; nt++)
#pragma unroll
            for (int jt = 0; jt < 4; jt++) {
                acc[nt][jt] = __builtin_amdgcn_mfma_f32_16x16x32_bf16(ah[nt], bh[jt], acc[nt][jt], 0, 0, 0);
                acc[nt][jt] = __builtin_amdgcn_mfma_f32_16x16x32_bf16(ah[nt], bl[jt], acc[nt][jt], 0, 0, 0);
                acc[nt][jt] = __builtin_amdgcn_mfma_f32_16x16x32_bf16(al[nt], bh[jt], acc[nt][jt], 0, 0, 0);
                acc[nt][jt] = __builtin_amdgcn_mfma_f32_16x16x32_bf16(al[nt], bl[jt], acc[nt][jt], 0, 0, 0);
            }
    }

#pragma unroll
    for (int jt = 0; jt < 4; jt++) {
        int j = wj * 64 + jt * 16 + l15;
        float bj = bias[j];
#pragma unroll
        for (int nt = 0; nt < 4; nt++) {
            int nb = n0 + wn * 64 + nt * 16 + quad * 4;
            f32x4 z = acc[nt][jt];
#pragma unroll
            for (int r = 0; r < 4; r++) z[r] += bj;
            if (LAYER == 1) {
#pragma unroll
                for (int r = 0; r < 4; r++) z[r] = 1.f / (1.f + __expf(-z[r]));
                if (j < 64) {
                    us4 h4, l4;
#pragma unroll
                    for (int r = 0; r < 4; r++) {
                        float x2 = z[r] * state[((size_t)b * NN + nb + r) * 64 + j];
                        ushort_t h, l; split_bf(x2, h, l);
                        h4[r] = h; l4[r] = l;
                    }
                    size_t ho = ((size_t)b * HB + 2 + j) * NN + nb;
                    *(us4*)&Hhw[ho] = h4;
                    *(us4*)&Hlw[ho] = l4;
                } else {
                    *(f32x4*)&U[((size_t)b * 64 + j - 64) * NN + nb] = z;
                }
            } else {
                f32x4 u4 = *(const f32x4*)&U[((size_t)b * 64 + j) * NN + nb];
#pragma unroll
                for (int r = 0; r < 4; r++) {
                    float c = tanhf(z[r]);
                    float s = state[((size_t)b * NN + nb + r) * 64 + j];
                    out[((size_t)b * NN + nb + r) * 64 + j] = u4[r] * s + (1.f - u4[r]) * c;
                }
            }
        }
    }
}

extern "C" void kernel_launch(void* const* d_in, const int* in_sizes, int n_in,
                              void* d_out, int out_size, void* d_ws, size_t ws_size,
                              hipStream_t stream) {
    const float* input = (const float*)d_in[0];
    const float* state = (const float*)d_in[1];
    const float* A0    = (const float*)d_in[2];
    const float* A1    = (const float*)d_in[3];
    const float* nv1_1 = (const float*)d_in[4];
    const float* nv2_1 = (const float*)d_in[5];
    const float* W1    = (const float*)d_in[6];
    const float* b1    = (const float*)d_in[7];
    const float* nv1_2 = (const float*)d_in[8];
    const float* nv2_2 = (const float*)d_in[9];
    const float* W2    = (const float*)d_in[10];
    const float* b2    = (const float*)d_in[11];
    float* out = (float*)d_out;

    char* p = (char*)d_ws;
    auto alloc = [&](size_t bytes) { void* r = (void*)p; p += (bytes + 255) & ~(size_t)255; return r; };
    float*    ADP1 = (float*)alloc(AN * 4);
    float*    ADP2 = (float*)alloc(AN * 4);
    ushort_t* Ahi  = (ushort_t*)alloc(4 * AN * 2);
    ushort_t* Alo  = (ushort_t*)alloc(4 * AN * 2);
    ushort_t* Hh   = (ushort_t*)alloc((size_t)BB * HB * NN * 2);
    ushort_t* Hl   = (ushort_t*)alloc((size_t)BB * HB * NN * 2);
    ushort_t* Wt1h = (ushort_t*)alloc((size_t)128 * KTOT * 2);
    ushort_t* Wt1l = (ushort_t*)alloc((size_t)128 * KTOT * 2);
    ushort_t* Wt2h = (ushort_t*)alloc((size_t)64 * KTOT * 2);
    ushort_t* Wt2l = (ushort_t*)alloc((size_t)64 * KTOT * 2);
    float*    U    = (float*)alloc((size_t)BB * 64 * NN * 4);

    adp_kernel<<<NN, NN, 0, stream>>>(nv1_1, nv2_1, ADP1);
    adp_kernel<<<NN, NN, 0, stream>>>(nv1_2, nv2_2, ADP2);
    asplit_kernel<<<dim3(16, 16, 4), 256, 0, stream>>>(A0, A1, ADP1, ADP2, Ahi, Alo);
    wtprep_kernel<128><<<128, 256, 0, stream>>>(W1, Wt1h, Wt1l);
    wtprep_kernel<64><<<64, 256, 0, stream>>>(W2, Wt2h, Wt2l);
    buildx_kernel<<<dim3(8, BB), 256, 0, stream>>>(input, state, Hh, Hl);

    dim3 gd(QQ / 128, NN / 128, 3);
    // layer 1
    diff_mfma<1><<<gd, 256, 0, stream>>>(Ahi, Alo, Hh, Hl, 2);
    diff_mfma<2><<<gd, 256, 0, stream>>>(Ahi, Alo, Hh, Hl, 2);
    proj_mfma<128, 1, 128><<<dim3(NN / 128, BB), 256, 0, stream>>>(Hh, Hl, Wt1h, Wt1l, b1, state,
                                                                   U, Hh, Hl, nullptr);
    // layer 2 (H rows 2..65 now hold r*state)
    diff_mfma<1><<<gd, 256, 0, stream>>>(Ahi, Alo, Hh, Hl, 3);
    diff_mfma<2><<<gd, 256, 0, stream>>>(Ahi, Alo, Hh, Hl, 3);
    proj_mfma<64, 2, 256><<<dim3(NN / 256, BB), 256, 0, stream>>>(Hh, Hl, Wt2h, Wt2l, b2, state,
                                                                  U, nullptr, nullptr, out);
}